// Round 1
// baseline (1079.452 us; speedup 1.0000x reference)
//
#include <hip/hip_runtime.h>
#include <math.h>

// Problem constants (from reference): B=8, S=1024, D=256, H=8, DH=32
constexpr int Bsz = 8, Ssz = 1024, Dsz = 256, Hn = 8, DHn = 32;
constexpr int RT = 8;    // query rows per attention block
constexpr int TJ = 128;  // K/V j-tile staged in LDS

#define DEV static __device__ __forceinline__

// ---------------- reduction helpers (256 threads = 4 waves of 64) ----------
DEV float waveRedMax(float v) {
#pragma unroll
  for (int off = 32; off > 0; off >>= 1) v = fmaxf(v, __shfl_xor(v, off, 64));
  return v;
}
DEV float waveRedSum(float v) {
#pragma unroll
  for (int off = 32; off > 0; off >>= 1) v += __shfl_xor(v, off, 64);
  return v;
}
DEV float blockMax(float v, float* red) {
  v = waveRedMax(v);
  const int w = threadIdx.x >> 6;
  if ((threadIdx.x & 63) == 0) red[w] = v;
  __syncthreads();
  float r = fmaxf(fmaxf(red[0], red[1]), fmaxf(red[2], red[3]));
  __syncthreads();
  return r;
}
DEV float blockSum(float v, float* red) {
  v = waveRedSum(v);
  const int w = threadIdx.x >> 6;
  if ((threadIdx.x & 63) == 0) red[w] = v;
  __syncthreads();
  float r = red[0] + red[1] + red[2] + red[3];
  __syncthreads();
  return r;
}
// exclusive prefix over the block; also returns total
DEV void blockScan(float v, float& excl, float& tot, float* red) {
  float x = v;
#pragma unroll
  for (int off = 1; off < 64; off <<= 1) {
    float y = __shfl_up(x, off, 64);
    if ((int)(threadIdx.x & 63) >= off) x += y;
  }
  const int w = threadIdx.x >> 6;
  if ((threadIdx.x & 63) == 63) red[w] = x;
  __syncthreads();
  const float r0 = red[0], r1 = red[1], r2 = red[2], r3 = red[3];
  const float woff = (w > 0 ? r0 : 0.f) + (w > 1 ? r1 : 0.f) + (w > 2 ? r2 : 0.f);
  __syncthreads();
  excl = woff + (x - v);
  tot  = r0 + r1 + r2 + r3;
}

// ---------------- GEMM: Y = X @ W^T + bias -------------------------------
// X: [M=8192, K=256] row-major, W: [N=256, K=256] row-major.
// HEADSPLIT=true writes Y in [B,H,S,DH] layout, else [M,N].
template <bool HEADSPLIT>
__global__ __launch_bounds__(256) void gemm_xwt(const float* __restrict__ X,
                                                const float* __restrict__ W,
                                                const float* __restrict__ bias,
                                                float* __restrict__ Y) {
  constexpr int K = 256, N = 256;
  constexpr int BM = 64, BN = 64, BK = 16;
  __shared__ float Xs[BK][BM + 1];
  __shared__ float Ws[BK][BN + 1];
  const int tid = threadIdx.x;
  const int bm = blockIdx.x & 127;  // M/BM = 128
  const int bn = blockIdx.x >> 7;   // N/BN = 4
  const int tx = tid & 15, ty = tid >> 4;
  float acc[4][4] = {};
  for (int k0 = 0; k0 < K; k0 += BK) {
#pragma unroll
    for (int i = tid; i < BM * BK; i += 256) {
      const int m = i >> 4, k = i & 15;
      Xs[k][m] = X[(size_t)(bm * BM + m) * K + k0 + k];
    }
#pragma unroll
    for (int i = tid; i < BN * BK; i += 256) {
      const int n = i >> 4, k = i & 15;
      Ws[k][n] = W[(size_t)(bn * BN + n) * K + k0 + k];
    }
    __syncthreads();
#pragma unroll
    for (int kk = 0; kk < BK; ++kk) {
      float a[4], b[4];
#pragma unroll
      for (int i = 0; i < 4; ++i) a[i] = Xs[kk][ty * 4 + i];
#pragma unroll
      for (int j = 0; j < 4; ++j) b[j] = Ws[kk][tx * 4 + j];
#pragma unroll
      for (int i = 0; i < 4; ++i)
#pragma unroll
        for (int j = 0; j < 4; ++j) acc[i][j] += a[i] * b[j];
    }
    __syncthreads();
  }
#pragma unroll
  for (int i = 0; i < 4; ++i) {
    const int m = bm * BM + ty * 4 + i;
#pragma unroll
    for (int j = 0; j < 4; ++j) {
      const int n = bn * BN + tx * 4 + j;
      const float v = acc[i][j] + bias[n];
      if (HEADSPLIT) {
        const int b = m >> 10, s = m & 1023;
        const int h = n >> 5, dh = n & 31;
        Y[((size_t)((b * Hn + h) << 10) + s) * DHn + dh] = v;
      } else {
        Y[(size_t)m * N + n] = v;
      }
    }
  }
}

// ---------------- fused attention -----------------------------------------
// One block handles RT=8 query rows of one (b,h). qh/kh/vh: [B,H,S,DH].
// Writes final probs to scores_out [B,H,S,S] and attention output (concat
// layout [B,S,H*DH]) to oc.
__global__ __launch_bounds__(256) void attn_kernel(const float* __restrict__ qh,
                                                   const float* __restrict__ kh,
                                                   const float* __restrict__ vh,
                                                   const float* __restrict__ gammas,
                                                   float* __restrict__ scores_out,
                                                   float* __restrict__ oc) {
  __shared__ float sK[TJ][DHn + 1];  // K tile, later V tile (pad -> no conflicts)
  __shared__ float ss[RT][Ssz];      // score rows, later prob rows
  __shared__ float sq[RT][DHn];
  __shared__ float red[4];

  const int tid = threadIdx.x;
  const int nrt = Ssz / RT;  // 128 row-tiles per (b,h)
  const int bh = blockIdx.x / nrt;
  const int rt = blockIdx.x % nrt;
  const int h = bh & 7;
  const int row0 = rt * RT;
  const float scale = 0.17677669529663687f;  // 1/sqrt(32)
  const float g = -fabsf(gammas[h]);
  const size_t baseKV = (size_t)bh * Ssz * DHn;

  // load the 8 query rows
  for (int i = tid; i < RT * DHn; i += 256) {
    const int r = i >> 5, d = i & 31;
    sq[r][d] = qh[baseKV + (size_t)(row0 + r) * DHn + d];
  }
  __syncthreads();

  const int rg = tid >> 5;  // row group 0..7
  const int jl = tid & 31;

  // ---- phase 1: raw scores into ss ----
  for (int jt = 0; jt < Ssz / TJ; ++jt) {
    for (int i = tid * 4; i < TJ * DHn; i += 1024) {
      const float4 kv = *(const float4*)&kh[baseKV + (size_t)jt * TJ * DHn + i];
      const int j = i >> 5, d = i & 31;
      sK[j][d] = kv.x; sK[j][d + 1] = kv.y; sK[j][d + 2] = kv.z; sK[j][d + 3] = kv.w;
    }
    __syncthreads();
#pragma unroll
    for (int q = 0; q < TJ / 32; ++q) {
      const int j = q * 32 + jl;
      float acc = 0.f;
#pragma unroll
      for (int k = 0; k < DHn; ++k) acc += sq[rg][k] * sK[j][k];
      ss[rg][jt * TJ + j] = acc * scale;
    }
    __syncthreads();
  }

  // ---- phase 2: per-row softmax #1 -> decay -> softmax #2 ----
  const int j0 = tid * 4;
  for (int r2 = 0; r2 < RT; ++r2) {
    const int irow = row0 + r2;
    float sv[4];
#pragma unroll
    for (int c = 0; c < 4; ++c) sv[c] = ss[r2][j0 + c];

    float lm = -INFINITY;
#pragma unroll
    for (int c = 0; c < 4; ++c)
      if (j0 + c <= irow) lm = fmaxf(lm, sv[c]);
    const float m1 = blockMax(lm, red);

    float e[4]; float ls = 0.f;
#pragma unroll
    for (int c = 0; c < 4; ++c) {
      e[c] = (j0 + c <= irow) ? __expf(sv[c] - m1) : 0.f;
      ls += e[c];
    }
    float excl, Z;
    blockScan(ls, excl, Z, red);
    const float invZ = 1.f / Z;

    float s2[4]; float cum = excl;
#pragma unroll
    for (int c = 0; c < 4; ++c) {
      cum += e[c];
      const float tail = (Z - cum) * invZ;               // sum_{l>j} softmax1
      const float pos = fabsf((float)(irow - (j0 + c)));
      const float dist = sqrtf(fmaxf(tail * pos, 0.f));
      float eff = __expf(g * dist);
      eff = fminf(fmaxf(eff, 1e-5f), 1e5f);
      s2[c] = sv[c] * eff;                               // raw score * effect
    }

    float lm2 = -INFINITY;
#pragma unroll
    for (int c = 0; c < 4; ++c)
      if (j0 + c <= irow) lm2 = fmaxf(lm2, s2[c]);
    const float m2 = blockMax(lm2, red);

    float p[4]; float ls2 = 0.f;
#pragma unroll
    for (int c = 0; c < 4; ++c) {
      p[c] = (j0 + c <= irow) ? __expf(s2[c] - m2) : 0.f;
      ls2 += p[c];
    }
    const float Z2 = blockSum(ls2, red);
    const float inv2 = 1.f / Z2;
#pragma unroll
    for (int c = 0; c < 4; ++c) p[c] *= inv2;

#pragma unroll
    for (int c = 0; c < 4; ++c) ss[r2][j0 + c] = p[c];   // keep for PV
    const float4 pv = make_float4(p[0], p[1], p[2], p[3]);
    *(float4*)&scores_out[((size_t)(bh * Ssz + irow)) * Ssz + j0] = pv;
  }

  // ---- phase 3: PV. one output element per thread ----
  float oacc = 0.f;
  const int pr = tid >> 5;  // row 0..7
  const int pd = tid & 31;  // dim 0..31
  for (int jt = 0; jt < Ssz / TJ; ++jt) {
    __syncthreads();  // prob writes (first iter) / previous tile reads done
    for (int i = tid * 4; i < TJ * DHn; i += 1024) {
      const float4 vv = *(const float4*)&vh[baseKV + (size_t)jt * TJ * DHn + i];
      const int j = i >> 5, d = i & 31;
      sK[j][d] = vv.x; sK[j][d + 1] = vv.y; sK[j][d + 2] = vv.z; sK[j][d + 3] = vv.w;
    }
    __syncthreads();
#pragma unroll 8
    for (int jj = 0; jj < TJ; ++jj) oacc += ss[pr][jt * TJ + jj] * sK[jj][pd];
  }
  const int b = bh >> 3;
  oc[((size_t)(b * Ssz + row0 + pr)) * Dsz + h * DHn + pd] = oacc;
}

// ---------------- launch ---------------------------------------------------
extern "C" void kernel_launch(void* const* d_in, const int* in_sizes, int n_in,
                              void* d_out, int out_size, void* d_ws, size_t ws_size,
                              hipStream_t stream) {
  const float* q  = (const float*)d_in[0];
  const float* k  = (const float*)d_in[1];
  const float* v  = (const float*)d_in[2];
  // d_in[3] is the causal tril mask — deterministic, not needed
  const float* Wq = (const float*)d_in[4];
  const float* bq = (const float*)d_in[5];
  const float* Wv = (const float*)d_in[6];
  const float* bv = (const float*)d_in[7];
  const float* Wo = (const float*)d_in[8];
  const float* bo = (const float*)d_in[9];
  const float* gm = (const float*)d_in[10];

  float* out    = (float*)d_out;                         // [B,S,D]
  float* scores = out + (size_t)Bsz * Ssz * Dsz;         // [B,H,S,S]

  float* ws = (float*)d_ws;
  const size_t Q = (size_t)Bsz * Hn * Ssz * DHn;         // 2,097,152 floats
  float* qh = ws;          // [B,H,S,DH]
  float* kh = ws + Q;
  float* vh = ws + 2 * Q;
  float* oc = ws + 3 * Q;  // concat [B,S,D]   (total ws use: 33.5 MB)

  const dim3 blk(256);
  const dim3 gemmGrid(512);  // (8192/64) * (256/64)

  hipLaunchKernelGGL((gemm_xwt<true>),  gemmGrid, blk, 0, stream, q, Wq, bq, qh);
  hipLaunchKernelGGL((gemm_xwt<true>),  gemmGrid, blk, 0, stream, k, Wq, bq, kh);
  hipLaunchKernelGGL((gemm_xwt<true>),  gemmGrid, blk, 0, stream, v, Wv, bv, vh);
  hipLaunchKernelGGL(attn_kernel, dim3(Bsz * Hn * (Ssz / RT)), blk, 0, stream,
                     qh, kh, vh, gm, scores, oc);
  hipLaunchKernelGGL((gemm_xwt<false>), gemmGrid, blk, 0, stream, oc, Wo, bo, out);
}

// Round 2
// 482.013 us; speedup vs baseline: 2.2395x; 2.2395x over previous
//
#include <hip/hip_runtime.h>
#include <math.h>

// B=8, S=1024, D=256, H=8, DH=32
constexpr int Bsz = 8, Ssz = 1024, Dsz = 256, Hn = 8, DHn = 32;

typedef __attribute__((ext_vector_type(8))) short short8;
typedef __attribute__((ext_vector_type(4))) float floatx4;

#define DEV static __device__ __forceinline__

// fp32 -> bf16 round-to-nearest-even
DEV short f2bf(float f) {
  union { float f; unsigned u; } x; x.f = f;
  return (short)((x.u + 0x7fffu + ((x.u >> 16) & 1u)) >> 16);
}
DEV short8 pack8(const float* v) {
  short8 r;
#pragma unroll
  for (int i = 0; i < 8; ++i) r[i] = f2bf(v[i]);
  return r;
}
DEV float wmax(float v) {
#pragma unroll
  for (int off = 32; off > 0; off >>= 1) v = fmaxf(v, __shfl_xor(v, off, 64));
  return v;
}
DEV float wsum(float v) {
#pragma unroll
  for (int off = 32; off > 0; off >>= 1) v += __shfl_xor(v, off, 64);
  return v;
}
DEV float wscan_incl(float v) {  // inclusive prefix over 64 lanes
  float x = v;
  const int ln = threadIdx.x & 63;
#pragma unroll
  for (int off = 1; off < 64; off <<= 1) {
    float y = __shfl_up(x, off, 64);
    if (ln >= off) x += y;
  }
  return x;
}

// ---------------- projection GEMM: Y = X @ W^T + bias (bf16 MFMA) ----------
// X: [8192, 256] (fp32 or bf16 per ABF16), W: [256,256] fp32 row-major.
// MODE 0: Y bf16 head-split [B,H,S,DH]; MODE 1: Y bf16 [B,H,DH,S] (V^T);
// MODE 2: Y fp32 [M,N].
template <int MODE, bool ABF16>
__global__ __launch_bounds__(256) void proj_gemm(const void* __restrict__ Aptr,
                                                 const float* __restrict__ W,
                                                 const float* __restrict__ bias,
                                                 void* __restrict__ Yptr) {
  constexpr int K = 256;
  const int tid = threadIdx.x, ln = tid & 63, w = tid >> 6;
  const int bm = blockIdx.x & 127, bn = blockIdx.x >> 7;
  const int m_base = bm * 64 + (w & 1) * 32;
  const int n_base = bn * 64 + (w >> 1) * 32;
  const int lm = ln & 15, q = ln >> 4;

  const float* Af = (const float*)Aptr;
  const short* Ab = (const short*)Aptr;
  floatx4 acc[2][2] = {};

#pragma unroll 2
  for (int k0 = 0; k0 < K; k0 += 32) {
    short8 a[2], b[2];
#pragma unroll
    for (int mt = 0; mt < 2; ++mt) {
      const int row = m_base + mt * 16 + lm;
      if (ABF16) {
        a[mt] = *(const short8*)(Ab + (size_t)row * K + k0 + q * 8);
      } else {
        const float* p = Af + (size_t)row * K + k0 + q * 8;
        float4 x = *(const float4*)p, y = *(const float4*)(p + 4);
        float t[8] = {x.x, x.y, x.z, x.w, y.x, y.y, y.z, y.w};
        a[mt] = pack8(t);
      }
    }
#pragma unroll
    for (int nt = 0; nt < 2; ++nt) {
      const int row = n_base + nt * 16 + lm;
      const float* p = W + (size_t)row * K + k0 + q * 8;
      float4 x = *(const float4*)p, y = *(const float4*)(p + 4);
      float t[8] = {x.x, x.y, x.z, x.w, y.x, y.y, y.z, y.w};
      b[nt] = pack8(t);
    }
#pragma unroll
    for (int mt = 0; mt < 2; ++mt)
#pragma unroll
      for (int nt = 0; nt < 2; ++nt)
        acc[mt][nt] = __builtin_amdgcn_mfma_f32_16x16x32_bf16(a[mt], b[nt], acc[mt][nt], 0, 0, 0);
  }

#pragma unroll
  for (int mt = 0; mt < 2; ++mt) {
#pragma unroll
    for (int nt = 0; nt < 2; ++nt) {
      const int n = n_base + nt * 16 + lm;
      const float bv = bias[n];
      const int m0 = m_base + mt * 16 + q * 4;
      if (MODE == 2) {
        float* Yf = (float*)Yptr;
#pragma unroll
        for (int r = 0; r < 4; ++r)
          Yf[(size_t)(m0 + r) * 256 + n] = acc[mt][nt][r] + bv;
      } else if (MODE == 0) {
        short* Yb = (short*)Yptr;
        const int h = n >> 5, dh = n & 31;
#pragma unroll
        for (int r = 0; r < 4; ++r) {
          const int m = m0 + r, b_ = m >> 10, s = m & 1023;
          Yb[(((size_t)(b_ * Hn + h) << 10) + s) * DHn + dh] = f2bf(acc[mt][nt][r] + bv);
        }
      } else {  // MODE 1: V^T [B,H,DH,S]
        short* Yb = (short*)Yptr;
        const int h = n >> 5, dh = n & 31;
        const int b_ = m0 >> 10, s0 = m0 & 1023;
        short4 pk;
        pk.x = f2bf(acc[mt][nt][0] + bv);
        pk.y = f2bf(acc[mt][nt][1] + bv);
        pk.z = f2bf(acc[mt][nt][2] + bv);
        pk.w = f2bf(acc[mt][nt][3] + bv);
        *(short4*)(Yb + ((size_t)((b_ * Hn + h) * DHn + dh) << 10) + s0) = pk;
      }
    }
  }
}

// ---------------- fused attention (MFMA) -----------------------------------
// Block = 16 query rows of one (b,h). qh/kh bf16 [B,H,S,DH]; vt bf16 [B,H,DH,S].
constexpr int SSTR = 1057;  // odd fp32 row stride -> <=2-way LDS conflicts
DEV int physcol(int c) { return c + (c >> 5); }

__global__ __launch_bounds__(256) void attn_kernel(const short* __restrict__ qh,
                                                   const short* __restrict__ kh,
                                                   const short* __restrict__ vt,
                                                   const float* __restrict__ gammas,
                                                   float* __restrict__ scores_out,
                                                   short* __restrict__ oc) {
  __shared__ float ss[16 * SSTR];       // 67,648 B: raw scores then probs
  __shared__ float red[4 * 16 * 32];    // 8,192 B: cross-wave PV reduction

  const int tid = threadIdx.x, ln = tid & 63, w = tid >> 6;
  const int lm = ln & 15, q = ln >> 4;
  const int bh = blockIdx.x >> 6;        // 64 row-tiles per (b,h)
  const int row0 = (blockIdx.x & 63) * 16;
  const int h = bh & 7, b = bh >> 3;
  const int lastcol = row0 + 15;
  const float scale = 0.17677669529663687f;  // 1/sqrt(32)
  const float g = -fabsf(gammas[h]);

  const short* qhead = qh + (size_t)bh * Ssz * DHn;
  const short* khead = kh + (size_t)bh * Ssz * DHn;
  const short* vhead = vt + (size_t)bh * DHn * Ssz;

  // Q A-frag: whole 16x32 tile in one frag (K=32=DH)
  const short8 qa = *(const short8*)(qhead + (row0 + lm) * DHn + q * 8);

  // ---- phase 1: QK^T -> raw scaled scores in LDS (causal tiles skipped) ----
  for (int t = w; t < 64; t += 4) {
    const int n0 = t * 16;
    if (n0 > lastcol) break;
    const short8 kb = *(const short8*)(khead + (n0 + lm) * DHn + q * 8);
    floatx4 c = {0.f, 0.f, 0.f, 0.f};
    c = __builtin_amdgcn_mfma_f32_16x16x32_bf16(qa, kb, c, 0, 0, 0);
    const int col = n0 + lm;
    const int pc = physcol(col);
#pragma unroll
    for (int r = 0; r < 4; ++r) ss[(q * 4 + r) * SSTR + pc] = c[r] * scale;
  }
  __syncthreads();

  // ---- phase 2: per-wave rows: softmax1 -> cumsum decay -> softmax2 ----
  for (int rr = 0; rr < 4; ++rr) {
    const int m = w * 4 + rr;
    const int irow = row0 + m;
    const int c0 = ln * 16;
    const float* srow = &ss[m * SSTR + physcol(c0)];
    float sv[16];
#pragma unroll
    for (int p = 0; p < 16; ++p) sv[p] = srow[p];
    const int nv = min(max(irow - c0 + 1, 0), 16);  // valid cols in my chunk

    float lm1 = -INFINITY;
#pragma unroll
    for (int p = 0; p < 16; ++p) if (p < nv) lm1 = fmaxf(lm1, sv[p]);
    const float m1 = wmax(lm1);

    float e[16], ls = 0.f;
#pragma unroll
    for (int p = 0; p < 16; ++p) { e[p] = (p < nv) ? __expf(sv[p] - m1) : 0.f; ls += e[p]; }
    const float incl = wscan_incl(ls);
    const float Z = __shfl(incl, 63, 64);
    const float excl = incl - ls;
    const float invZ = 1.f / Z;

    float s2[16], lm2 = -INFINITY, cum = excl;
#pragma unroll
    for (int p = 0; p < 16; ++p) {
      cum += e[p];
      const float tail = (Z - cum) * invZ;
      const float pos = (float)(irow - (c0 + p));
      const float dist = sqrtf(fmaxf(tail * pos, 0.f));
      float eff = __expf(g * dist);
      eff = fminf(fmaxf(eff, 1e-5f), 1e5f);
      s2[p] = sv[p] * eff;
      if (p < nv) lm2 = fmaxf(lm2, s2[p]);
    }
    const float m2 = wmax(lm2);

    float pv[16], ls2 = 0.f;
#pragma unroll
    for (int p = 0; p < 16; ++p) { pv[p] = (p < nv) ? __expf(s2[p] - m2) : 0.f; ls2 += pv[p]; }
    const float i2 = 1.f / wsum(ls2);

    float* grow = scores_out + ((size_t)(bh << 10) + irow) * Ssz + c0;
    float* wrow = &ss[m * SSTR + physcol(c0)];
#pragma unroll
    for (int p = 0; p < 16; p += 4) {
      float4 o;
      o.x = pv[p] * i2; o.y = pv[p + 1] * i2; o.z = pv[p + 2] * i2; o.w = pv[p + 3] * i2;
      *(float4*)(grow + p) = o;
      wrow[p] = o.x; wrow[p + 1] = o.y; wrow[p + 2] = o.z; wrow[p + 3] = o.w;
    }
  }
  __syncthreads();

  // ---- phase 3: PV via MFMA, K split across waves (causal skip) ----
  floatx4 o0 = {0.f, 0.f, 0.f, 0.f}, o1 = {0.f, 0.f, 0.f, 0.f};
  for (int kt = w; kt < 32; kt += 4) {
    const int k0 = kt * 32;
    if (k0 > lastcol) break;
    const float* ap = &ss[lm * SSTR + physcol(k0) + q * 8];
    float t[8];
#pragma unroll
    for (int j = 0; j < 8; ++j) t[j] = ap[j];
    const short8 av = pack8(t);
    const short8 b0 = *(const short8*)(vhead + (lm << 10) + k0 + q * 8);
    const short8 b1 = *(const short8*)(vhead + ((16 + lm) << 10) + k0 + q * 8);
    o0 = __builtin_amdgcn_mfma_f32_16x16x32_bf16(av, b0, o0, 0, 0, 0);
    o1 = __builtin_amdgcn_mfma_f32_16x16x32_bf16(av, b1, o1, 0, 0, 0);
  }
#pragma unroll
  for (int r = 0; r < 4; ++r) {
    red[(w * 16 + q * 4 + r) * 32 + lm] = o0[r];
    red[(w * 16 + q * 4 + r) * 32 + 16 + lm] = o1[r];
  }
  __syncthreads();

  // cross-wave reduce + bf16 store to oc [B,S,D]
  {
    const int m = tid >> 4, n = tid & 15;
    float a0 = 0.f, a1 = 0.f;
#pragma unroll
    for (int wv = 0; wv < 4; ++wv) {
      a0 += red[(wv * 16 + m) * 32 + n];
      a1 += red[(wv * 16 + m) * 32 + 16 + n];
    }
    const size_t row = ((size_t)b << 10) + row0 + m;
    oc[row * Dsz + h * DHn + n] = f2bf(a0);
    oc[row * Dsz + h * DHn + 16 + n] = f2bf(a1);
  }
}

// ---------------- launch ---------------------------------------------------
extern "C" void kernel_launch(void* const* d_in, const int* in_sizes, int n_in,
                              void* d_out, int out_size, void* d_ws, size_t ws_size,
                              hipStream_t stream) {
  const float* q  = (const float*)d_in[0];
  const float* k  = (const float*)d_in[1];
  const float* v  = (const float*)d_in[2];
  const float* Wq = (const float*)d_in[4];
  const float* bq = (const float*)d_in[5];
  const float* Wv = (const float*)d_in[6];
  const float* bv = (const float*)d_in[7];
  const float* Wo = (const float*)d_in[8];
  const float* bo = (const float*)d_in[9];
  const float* gm = (const float*)d_in[10];

  float* out    = (float*)d_out;                  // [B,S,D] fp32
  float* scores = out + (size_t)Bsz * Ssz * Dsz;  // [B,H,S,S] fp32

  const size_t Q = (size_t)Bsz * Hn * Ssz * DHn;  // 2,097,152 elems
  short* qh  = (short*)d_ws;       // bf16 [B,H,S,DH]
  short* kh  = qh + Q;
  short* vtT = kh + Q;             // bf16 [B,H,DH,S]
  short* oc  = vtT + Q;            // bf16 [B,S,D]   (total 16 MB)

  const dim3 blk(256);
  hipLaunchKernelGGL((proj_gemm<0, false>), dim3(512), blk, 0, stream, q, Wq, bq, qh);
  hipLaunchKernelGGL((proj_gemm<0, false>), dim3(512), blk, 0, stream, k, Wq, bq, kh);
  hipLaunchKernelGGL((proj_gemm<1, false>), dim3(512), blk, 0, stream, v, Wv, bv, vtT);
  hipLaunchKernelGGL(attn_kernel, dim3(Bsz * Hn * (Ssz / 16)), blk, 0, stream,
                     qh, kh, vtT, gm, scores, oc);
  hipLaunchKernelGGL((proj_gemm<2, true>), dim3(512), blk, 0, stream, oc, Wo, bo, out);
}

// Round 3
// 395.468 us; speedup vs baseline: 2.7296x; 1.2188x over previous
//
#include <hip/hip_runtime.h>
#include <hip/hip_fp16.h>
#include <math.h>

// B=8, S=1024, D=256, H=8, DH=32
constexpr int Bsz = 8, Ssz = 1024, Dsz = 256, Hn = 8, DHn = 32;
constexpr int SST = 1160;  // attn LDS row stride in shorts (SST/8 odd -> good b128 spread)

typedef __attribute__((ext_vector_type(8))) short short8;
typedef __attribute__((ext_vector_type(4))) float floatx4;

#define DEV static __device__ __forceinline__

DEV short f2bf(float f) {  // fp32 -> bf16 RNE
  union { float f; unsigned u; } x; x.f = f;
  return (short)((x.u + 0x7fffu + ((x.u >> 16) & 1u)) >> 16);
}
DEV short f2h(float f) {  // fp32 -> fp16 bits
  __half h = __float2half(f);
  return *(short*)&h;
}
DEV float wmax(float v) {
#pragma unroll
  for (int off = 32; off > 0; off >>= 1) v = fmaxf(v, __shfl_xor(v, off, 64));
  return v;
}
DEV float wsum(float v) {
#pragma unroll
  for (int off = 32; off > 0; off >>= 1) v += __shfl_xor(v, off, 64);
  return v;
}
DEV float wscan_incl(float v) {
  float x = v;
  const int ln = threadIdx.x & 63;
#pragma unroll
  for (int off = 1; off < 64; off <<= 1) {
    float y = __shfl_up(x, off, 64);
    if (ln >= off) x += y;
  }
  return x;
}

// ================= projection GEMMs (LDS-staged bf16 MFMA) =================
// stage a 64x64 fp32 tile (row stride 256 floats) into bf16 LDS [64][80],
// granule-XOR swizzled. 256 threads.
DEV void stage_f32(const float* __restrict__ src, short* dst, int k0, int tid) {
  const int row = tid >> 2, cg = tid & 3;
#pragma unroll
  for (int i = 0; i < 4; ++i) {
    const float4 f = *(const float4*)(src + (size_t)row * 256 + k0 + cg * 16 + i * 4);
    const int g = cg * 2 + (i >> 1);
    const int pg = g ^ (row & 7);
    short4 s; s.x = f2bf(f.x); s.y = f2bf(f.y); s.z = f2bf(f.z); s.w = f2bf(f.w);
    *(short4*)(dst + row * 80 + pg * 8 + (i & 1) * 4) = s;
  }
}
DEV void stage_bf16(const short* __restrict__ src, short* dst, int k0, int tid) {
  const int row = tid >> 2, cg = tid & 3;
#pragma unroll
  for (int i = 0; i < 2; ++i) {
    const short8 s = *(const short8*)(src + (size_t)row * 256 + k0 + cg * 16 + i * 8);
    const int pg = (cg * 2 + i) ^ (row & 7);
    *(short8*)(dst + row * 80 + pg * 8) = s;
  }
}

// fused q/k/v projections. gridDim = (512, 3). MODE by blockIdx.y:
// y=0: q@Wq^T+bq -> qh [B,H,S,DH] bf16 ; y=1: same for k -> kh ;
// y=2: v@Wv^T+bv -> vt [B,H,DH,S] bf16 (transposed for PV B-frags)
__global__ __launch_bounds__(256, 4) void proj_qkv(
    const float* __restrict__ qi, const float* __restrict__ ki, const float* __restrict__ vi,
    const float* __restrict__ Wq, const float* __restrict__ bq,
    const float* __restrict__ Wv, const float* __restrict__ bv,
    short* __restrict__ qh, short* __restrict__ kh, short* __restrict__ vt) {
  __shared__ short As[64 * 80];
  __shared__ short Bs[64 * 80];
  const int which = blockIdx.y;
  const float* X = (which == 0) ? qi : (which == 1) ? ki : vi;
  const float* W = (which == 2) ? Wv : Wq;
  const float* bias = (which == 2) ? bv : bq;
  const int tid = threadIdx.x, ln = tid & 63, w = tid >> 6;
  const int lm = ln & 15, qq = ln >> 4;
  const int bm = blockIdx.x & 127, bn = blockIdx.x >> 7;
  const float* Xb = X + (size_t)bm * 64 * 256;
  const float* Wb = W + (size_t)bn * 64 * 256;
  const int moff = (w & 1) * 32, noff = (w >> 1) * 32;
  floatx4 acc[2][2] = {};

  for (int k0 = 0; k0 < 256; k0 += 64) {
    __syncthreads();
    stage_f32(Xb, As, k0, tid);
    stage_f32(Wb, Bs, k0, tid);
    __syncthreads();
#pragma unroll
    for (int ks = 0; ks < 2; ++ks) {
      short8 a[2], b[2];
#pragma unroll
      for (int mt = 0; mt < 2; ++mt) {
        const int row = moff + mt * 16 + lm;
        a[mt] = *(const short8*)(As + row * 80 + ((ks * 4 + qq) ^ (row & 7)) * 8);
      }
#pragma unroll
      for (int nt = 0; nt < 2; ++nt) {
        const int row = noff + nt * 16 + lm;
        b[nt] = *(const short8*)(Bs + row * 80 + ((ks * 4 + qq) ^ (row & 7)) * 8);
      }
#pragma unroll
      for (int mt = 0; mt < 2; ++mt)
#pragma unroll
        for (int nt = 0; nt < 2; ++nt)
          acc[mt][nt] = __builtin_amdgcn_mfma_f32_16x16x32_bf16(a[mt], b[nt], acc[mt][nt], 0, 0, 0);
    }
  }

  short* dst = (which == 0) ? qh : (which == 1) ? kh : vt;
#pragma unroll
  for (int mt = 0; mt < 2; ++mt) {
#pragma unroll
    for (int nt = 0; nt < 2; ++nt) {
      const int n = bn * 64 + noff + nt * 16 + lm;
      const float bval = bias[n];
      const int m0 = bm * 64 + moff + mt * 16 + qq * 4;
      const int h = n >> 5, dh = n & 31;
      if (which <= 1) {  // head-split [B,H,S,DH]
#pragma unroll
        for (int r = 0; r < 4; ++r) {
          const int m = m0 + r, b_ = m >> 10, s = m & 1023;
          dst[(((size_t)(b_ * Hn + h) << 10) + s) * DHn + dh] = f2bf(acc[mt][nt][r] + bval);
        }
      } else {  // V^T [B,H,DH,S]
        const int b_ = m0 >> 10, s0 = m0 & 1023;
        short4 pk;
        pk.x = f2bf(acc[mt][nt][0] + bval);
        pk.y = f2bf(acc[mt][nt][1] + bval);
        pk.z = f2bf(acc[mt][nt][2] + bval);
        pk.w = f2bf(acc[mt][nt][3] + bval);
        *(short4*)(dst + ((size_t)((b_ * Hn + h) * DHn + dh) << 10) + s0) = pk;
      }
    }
  }
}

// output projection: oc(bf16 [8192,256]) @ Wo^T + bo -> out fp32 [8192,256]
__global__ __launch_bounds__(256, 4) void proj_out(
    const short* __restrict__ oc, const float* __restrict__ Wo,
    const float* __restrict__ bo, float* __restrict__ out) {
  __shared__ short As[64 * 80];
  __shared__ short Bs[64 * 80];
  const int tid = threadIdx.x, ln = tid & 63, w = tid >> 6;
  const int lm = ln & 15, qq = ln >> 4;
  const int bm = blockIdx.x & 127, bn = blockIdx.x >> 7;
  const short* Xb = oc + (size_t)bm * 64 * 256;
  const float* Wb = Wo + (size_t)bn * 64 * 256;
  const int moff = (w & 1) * 32, noff = (w >> 1) * 32;
  floatx4 acc[2][2] = {};

  for (int k0 = 0; k0 < 256; k0 += 64) {
    __syncthreads();
    stage_bf16(Xb, As, k0, tid);
    stage_f32(Wb, Bs, k0, tid);
    __syncthreads();
#pragma unroll
    for (int ks = 0; ks < 2; ++ks) {
      short8 a[2], b[2];
#pragma unroll
      for (int mt = 0; mt < 2; ++mt) {
        const int row = moff + mt * 16 + lm;
        a[mt] = *(const short8*)(As + row * 80 + ((ks * 4 + qq) ^ (row & 7)) * 8);
      }
#pragma unroll
      for (int nt = 0; nt < 2; ++nt) {
        const int row = noff + nt * 16 + lm;
        b[nt] = *(const short8*)(Bs + row * 80 + ((ks * 4 + qq) ^ (row & 7)) * 8);
      }
#pragma unroll
      for (int mt = 0; mt < 2; ++mt)
#pragma unroll
        for (int nt = 0; nt < 2; ++nt)
          acc[mt][nt] = __builtin_amdgcn_mfma_f32_16x16x32_bf16(a[mt], b[nt], acc[mt][nt], 0, 0, 0);
    }
  }
#pragma unroll
  for (int mt = 0; mt < 2; ++mt)
#pragma unroll
    for (int nt = 0; nt < 2; ++nt) {
      const int n = bn * 64 + noff + nt * 16 + lm;
      const float bval = bo[n];
      const int m0 = bm * 64 + moff + mt * 16 + qq * 4;
#pragma unroll
      for (int r = 0; r < 4; ++r)
        out[(size_t)(m0 + r) * 256 + n] = acc[mt][nt][r] + bval;
    }
}

// ======================= fused attention ===================================
// phase 2: NP passes of 256 cols; lane ln owns cols ln*4 + 256p of each row.
template <int NP>
DEV void phase2(short* ss, float* shead, int row0, int w, int ln, float g) {
  const int c0 = ln * 4;
  for (int rr = 0; rr < 4; ++rr) {
    const int m = w * 4 + rr;
    const int irow = row0 + m;
    short* srow = ss + m * SST;

    float sv[NP * 4], e[NP * 4];
    float lm1 = -INFINITY;
#pragma unroll
    for (int p = 0; p < NP; ++p) {
      const uint2 u = *(const uint2*)(srow + p * 256 + c0);
      const float2 f0 = __half22float2(*(const __half2*)&u.x);
      const float2 f1 = __half22float2(*(const __half2*)&u.y);
      sv[p * 4 + 0] = f0.x; sv[p * 4 + 1] = f0.y;
      sv[p * 4 + 2] = f1.x; sv[p * 4 + 3] = f1.y;
#pragma unroll
      for (int j = 0; j < 4; ++j)
        if (p * 256 + c0 + j <= irow) lm1 = fmaxf(lm1, sv[p * 4 + j]);
    }
    const float m1 = wmax(lm1);

    float carry = 0.f, excl[NP];
#pragma unroll
    for (int p = 0; p < NP; ++p) {
      float ls = 0.f;
#pragma unroll
      for (int j = 0; j < 4; ++j) {
        const int c = p * 256 + c0 + j;
        e[p * 4 + j] = (c <= irow) ? __expf(sv[p * 4 + j] - m1) : 0.f;
        ls += e[p * 4 + j];
      }
      const float incl = wscan_incl(ls);
      excl[p] = carry + incl - ls;
      carry += __shfl(incl, 63, 64);
    }
    const float Z = carry, invZ = 1.f / Z;

    float lm2 = -INFINITY;
#pragma unroll
    for (int p = 0; p < NP; ++p) {
      float cum = excl[p];
#pragma unroll
      for (int j = 0; j < 4; ++j) {
        const int c = p * 256 + c0 + j;
        cum += e[p * 4 + j];
        const float tail = (Z - cum) * invZ;
        const float pos = (float)(irow - c);
        const float dist = sqrtf(fmaxf(tail * pos, 0.f));
        float eff = __expf(g * dist);
        eff = fminf(fmaxf(eff, 1e-5f), 1e5f);
        const float s2 = sv[p * 4 + j] * eff;
        sv[p * 4 + j] = s2;  // reuse
        if (c <= irow) lm2 = fmaxf(lm2, s2);
      }
    }
    const float m2 = wmax(lm2);

    float ls2 = 0.f;
#pragma unroll
    for (int p = 0; p < NP; ++p)
#pragma unroll
      for (int j = 0; j < 4; ++j) {
        const int c = p * 256 + c0 + j;
        e[p * 4 + j] = (c <= irow) ? __expf(sv[p * 4 + j] - m2) : 0.f;  // reuse e as p2
        ls2 += e[p * 4 + j];
      }
    const float i2 = 1.f / wsum(ls2);

    float* grow = shead + (size_t)irow * Ssz;
#pragma unroll
    for (int p = 0; p < NP; ++p) {
      float4 o;
      o.x = e[p * 4 + 0] * i2; o.y = e[p * 4 + 1] * i2;
      o.z = e[p * 4 + 2] * i2; o.w = e[p * 4 + 3] * i2;
      *(float4*)(grow + p * 256 + c0) = o;
      uint2 pk;
      pk.x = (uint)(unsigned short)f2bf(o.x) | ((uint)(unsigned short)f2bf(o.y) << 16);
      pk.y = (uint)(unsigned short)f2bf(o.z) | ((uint)(unsigned short)f2bf(o.w) << 16);
      *(uint2*)(srow + p * 256 + c0) = pk;  // probs (bf16) overwrite raw scores
    }
  }
}

__global__ __launch_bounds__(256, 4) void attn_kernel(
    const short* __restrict__ qh, const short* __restrict__ kh,
    const short* __restrict__ vt, const float* __restrict__ gammas,
    float* __restrict__ scores_out, short* __restrict__ oc) {
  __shared__ short ss[16 * SST];  // 37,120 B: fp16 raw scores -> bf16 probs

  const int tid = threadIdx.x, ln = tid & 63, w = tid >> 6;
  const int lm = ln & 15, qq = ln >> 4;
  const int bh = blockIdx.x >> 6;
  const int row0 = (63 - (blockIdx.x & 63)) << 4;  // heavy tiles first
  const int h = bh & 7, b = bh >> 3;
  const float scale = 0.17677669529663687f;  // 1/sqrt(32)
  const float g = -fabsf(gammas[h]);

  const short* qhead = qh + (size_t)bh * Ssz * DHn;
  const short* khead = kh + (size_t)bh * Ssz * DHn;
  const short* vhead = vt + (size_t)bh * DHn * Ssz;
  float* shead = scores_out + ((size_t)bh << 20);

  const short8 qa = *(const short8*)(qhead + (row0 + lm) * DHn + qq * 8);

  // ---- phase 1: QK^T -> fp16 raw scores in LDS (causal tiles only) ----
  const int ntile = (row0 >> 4) + 1;
  for (int t = w; t < ntile; t += 4) {
    const int n0 = t * 16;
    const short8 kb = *(const short8*)(khead + (n0 + lm) * DHn + qq * 8);
    floatx4 c = {0.f, 0.f, 0.f, 0.f};
    c = __builtin_amdgcn_mfma_f32_16x16x32_bf16(qa, kb, c, 0, 0, 0);
#pragma unroll
    for (int r = 0; r < 4; ++r)
      ss[(qq * 4 + r) * SST + n0 + lm] = f2h(c[r] * scale);
  }
  __syncthreads();

  // ---- phase 2: softmax1 -> cumsum decay -> softmax2 (NP causal passes) ----
  const int NPc = (row0 >> 8) + 1;
  switch (NPc) {
    case 1: phase2<1>(ss, shead, row0, w, ln, g); break;
    case 2: phase2<2>(ss, shead, row0, w, ln, g); break;
    case 3: phase2<3>(ss, shead, row0, w, ln, g); break;
    default: phase2<4>(ss, shead, row0, w, ln, g); break;
  }

  // zero-fill masked tail of scores rows
  if (NPc < 4) {
    const float4 z4 = make_float4(0.f, 0.f, 0.f, 0.f);
    for (int r = 0; r < 16; ++r) {
      float* grow = shead + (size_t)(row0 + r) * Ssz + NPc * 256;
      for (int i = tid; i < (4 - NPc) * 64; i += 256)
        ((float4*)grow)[i] = z4;
    }
  }
  __syncthreads();

  // ---- phase 3: PV via MFMA (bf16 probs straight from LDS) ----
  floatx4 o0 = {0.f, 0.f, 0.f, 0.f}, o1 = {0.f, 0.f, 0.f, 0.f};
  const int nkt = (row0 >> 5) + 1;
  for (int kt = w; kt < nkt; kt += 4) {
    const int k0 = kt * 32;
    const short8 av = *(const short8*)(ss + lm * SST + k0 + qq * 8);
    const short8 b0 = *(const short8*)(vhead + (lm << 10) + k0 + qq * 8);
    const short8 b1 = *(const short8*)(vhead + ((16 + lm) << 10) + k0 + qq * 8);
    o0 = __builtin_amdgcn_mfma_f32_16x16x32_bf16(av, b0, o0, 0, 0, 0);
    o1 = __builtin_amdgcn_mfma_f32_16x16x32_bf16(av, b1, o1, 0, 0, 0);
  }
  __syncthreads();          // all prob reads done; alias ss as reduction buf
  float* red = (float*)ss;  // [4][16][32] = 8 KB
#pragma unroll
  for (int r = 0; r < 4; ++r) {
    red[(w * 16 + qq * 4 + r) * 32 + lm] = o0[r];
    red[(w * 16 + qq * 4 + r) * 32 + 16 + lm] = o1[r];
  }
  __syncthreads();
  {
    const int m = tid >> 4, n = tid & 15;
    float a0 = 0.f, a1 = 0.f;
#pragma unroll
    for (int wv = 0; wv < 4; ++wv) {
      a0 += red[(wv * 16 + m) * 32 + n];
      a1 += red[(wv * 16 + m) * 32 + 16 + n];
    }
    const size_t row = ((size_t)b << 10) + row0 + m;
    oc[row * Dsz + h * DHn + n] = f2bf(a0);
    oc[row * Dsz + h * DHn + 16 + n] = f2bf(a1);
  }
}

// ---------------- launch ---------------------------------------------------
extern "C" void kernel_launch(void* const* d_in, const int* in_sizes, int n_in,
                              void* d_out, int out_size, void* d_ws, size_t ws_size,
                              hipStream_t stream) {
  const float* q  = (const float*)d_in[0];
  const float* k  = (const float*)d_in[1];
  const float* v  = (const float*)d_in[2];
  const float* Wq = (const float*)d_in[4];
  const float* bq = (const float*)d_in[5];
  const float* Wv = (const float*)d_in[6];
  const float* bv = (const float*)d_in[7];
  const float* Wo = (const float*)d_in[8];
  const float* bo = (const float*)d_in[9];
  const float* gm = (const float*)d_in[10];

  float* out    = (float*)d_out;                  // [B,S,D] fp32
  float* scores = out + (size_t)Bsz * Ssz * Dsz;  // [B,H,S,S] fp32

  const size_t Q = (size_t)Bsz * Hn * Ssz * DHn;
  short* qh = (short*)d_ws;        // bf16 [B,H,S,DH]
  short* kh = qh + Q;
  short* vt = kh + Q;              // bf16 [B,H,DH,S]
  short* oc = vt + Q;              // bf16 [B,S,D]

  const dim3 blk(256);
  hipLaunchKernelGGL(proj_qkv, dim3(512, 3), blk, 0, stream,
                     q, k, v, Wq, bq, Wv, bv, qh, kh, vt);
  hipLaunchKernelGGL(attn_kernel, dim3(Bsz * Hn * (Ssz / 16)), blk, 0, stream,
                     qh, kh, vt, gm, scores, oc);
  hipLaunchKernelGGL(proj_out, dim3(512), blk, 0, stream, oc, Wo, bo, out);
}

// Round 5
// 381.186 us; speedup vs baseline: 2.8318x; 1.0375x over previous
//
#include <hip/hip_runtime.h>
#include <hip/hip_fp16.h>
#include <math.h>

// B=8, S=1024, D=256, H=8, DH=32
constexpr int Bsz = 8, Ssz = 1024, Dsz = 256, Hn = 8, DHn = 32;
constexpr int SST = 1160;  // attn LDS row stride in shorts

typedef __attribute__((ext_vector_type(8))) short short8;
typedef __attribute__((ext_vector_type(4))) float floatx4;

#define DEV static __device__ __forceinline__

DEV short f2bf(float f) {  // fp32 -> bf16 RNE
  union { float f; unsigned u; } x; x.f = f;
  return (short)((x.u + 0x7fffu + ((x.u >> 16) & 1u)) >> 16);
}
DEV short f2h(float f) {
  __half h = __float2half(f);
  return *(short*)&h;
}
DEV float wmax(float v) {
#pragma unroll
  for (int off = 32; off > 0; off >>= 1) v = fmaxf(v, __shfl_xor(v, off, 64));
  return v;
}
DEV float wsum(float v) {
#pragma unroll
  for (int off = 32; off > 0; off >>= 1) v += __shfl_xor(v, off, 64);
  return v;
}
DEV float wscan_incl(float v) {
  float x = v;
  const int ln = threadIdx.x & 63;
#pragma unroll
  for (int off = 1; off < 64; off <<= 1) {
    float y = __shfl_up(x, off, 64);
    if (ln >= off) x += y;
  }
  return x;
}

// ============ W pre-convert: fp32 row-major -> bf16 MFMA B-frag order =======
// layout: [kblk(8)][ntile(16)][lane(64)][8 bf16]; element =
//   W[ntile*16 + (lane&15)][kblk*32 + (lane>>4)*8 + j]
__global__ __launch_bounds__(256) void cvt_wfrag(const float* __restrict__ Wq,
                                                 const float* __restrict__ Wv,
                                                 const float* __restrict__ Wo,
                                                 short* __restrict__ dst) {
  const int which = blockIdx.y;
  const float* W = (which == 0) ? Wq : (which == 1) ? Wv : Wo;
  const int t = blockIdx.x * 256 + threadIdx.x;  // 0..8191
  const int ln = t & 63, nt = (t >> 6) & 15, kblk = t >> 10;
  const float* src = W + (size_t)(nt * 16 + (ln & 15)) * 256 + kblk * 32 + (ln >> 4) * 8;
  const float4 a = *(const float4*)src;
  const float4 b = *(const float4*)(src + 4);
  const float tmp[8] = {a.x, a.y, a.z, a.w, b.x, b.y, b.z, b.w};
  short8 s;
#pragma unroll
  for (int j = 0; j < 8; ++j) s[j] = f2bf(tmp[j]);
  *(short8*)(dst + ((size_t)which << 16) + (size_t)t * 8) = s;
}

// ============ projections: 32 rows x full N=256 per block ==================
// Xs: 32x80 bf16, granule-XOR swizzled. Wave w owns n-range [w*64, w*64+64).
__global__ __launch_bounds__(256, 4) void proj_qkv2(
    const float* __restrict__ qi, const float* __restrict__ ki, const float* __restrict__ vi,
    const short* __restrict__ Wfrag, const float* __restrict__ bq, const float* __restrict__ bv,
    short* __restrict__ qh, short* __restrict__ kh, short* __restrict__ vt) {
  __shared__ short Xs[32 * 80];
  const int which = blockIdx.y;
  const float* X = (which == 0) ? qi : (which == 1) ? ki : vi;
  const short* Wf = Wfrag + ((which == 2) ? (1 << 16) : 0);
  const float* bias = (which == 2) ? bv : bq;
  const int tid = threadIdx.x, ln = tid & 63, w = tid >> 6;
  const int lm = ln & 15, qq = ln >> 4;
  const int bm = blockIdx.x;  // 256 blocks of 32 rows
  const float* Xb = X + (size_t)bm * 32 * 256;
  floatx4 acc[2][4] = {};

  for (int k0 = 0; k0 < 4; ++k0) {
    __syncthreads();
    {
      const int row = tid >> 3, cg = tid & 7;
#pragma unroll
      for (int i = 0; i < 2; ++i) {
        const float4 f = *(const float4*)(Xb + (size_t)row * 256 + k0 * 64 + cg * 8 + i * 4);
        short4 s; s.x = f2bf(f.x); s.y = f2bf(f.y); s.z = f2bf(f.z); s.w = f2bf(f.w);
        *(short4*)(Xs + row * 80 + (cg ^ (row & 7)) * 8 + i * 4) = s;
      }
    }
    __syncthreads();
#pragma unroll
    for (int ks = 0; ks < 2; ++ks) {
      const int kblk = k0 * 2 + ks;
      short8 a[2], b[4];
#pragma unroll
      for (int mt = 0; mt < 2; ++mt) {
        const int row = mt * 16 + lm;
        a[mt] = *(const short8*)(Xs + row * 80 + (((ks * 4 + qq)) ^ (row & 7)) * 8);
      }
#pragma unroll
      for (int nt = 0; nt < 4; ++nt)
        b[nt] = *(const short8*)(Wf + ((size_t)(kblk * 16 + w * 4 + nt) * 64 + ln) * 8);
#pragma unroll
      for (int mt = 0; mt < 2; ++mt)
#pragma unroll
        for (int nt = 0; nt < 4; ++nt)
          acc[mt][nt] = __builtin_amdgcn_mfma_f32_16x16x32_bf16(a[mt], b[nt], acc[mt][nt], 0, 0, 0);
    }
  }

#pragma unroll
  for (int mt = 0; mt < 2; ++mt) {
#pragma unroll
    for (int nt = 0; nt < 4; ++nt) {
      const int n = w * 64 + nt * 16 + lm;
      const float bval = bias[n];
      const int m0 = bm * 32 + mt * 16 + qq * 4;
      const int h = n >> 5, dh = n & 31;
      if (which <= 1) {  // head-split [B,H,S,DH]
        short* dst = (which == 0) ? qh : kh;
#pragma unroll
        for (int r = 0; r < 4; ++r) {
          const int m = m0 + r, b_ = m >> 10, s = m & 1023;
          dst[(((size_t)(b_ * Hn + h) << 10) + s) * DHn + dh] = f2bf(acc[mt][nt][r] + bval);
        }
      } else {  // V^T [B,H,DH,S]
        const int b_ = m0 >> 10, s0 = m0 & 1023;
        short4 pk;
        pk.x = f2bf(acc[mt][nt][0] + bval);
        pk.y = f2bf(acc[mt][nt][1] + bval);
        pk.z = f2bf(acc[mt][nt][2] + bval);
        pk.w = f2bf(acc[mt][nt][3] + bval);
        *(short4*)(vt + ((size_t)((b_ * Hn + h) * DHn + dh) << 10) + s0) = pk;
      }
    }
  }
}

__global__ __launch_bounds__(256, 4) void proj_out2(
    const short* __restrict__ oc, const short* __restrict__ Wfrag,
    const float* __restrict__ bo, float* __restrict__ out) {
  __shared__ short Xs[32 * 80];
  const short* Wf = Wfrag + (2 << 16);
  const int tid = threadIdx.x, ln = tid & 63, w = tid >> 6;
  const int lm = ln & 15, qq = ln >> 4;
  const int bm = blockIdx.x;
  const short* Xb = oc + (size_t)bm * 32 * 256;
  floatx4 acc[2][4] = {};

  for (int k0 = 0; k0 < 4; ++k0) {
    __syncthreads();
    {
      const int row = tid >> 3, cg = tid & 7;
      const short8 s = *(const short8*)(Xb + (size_t)row * 256 + k0 * 64 + cg * 8);
      *(short8*)(Xs + row * 80 + (cg ^ (row & 7)) * 8) = s;
    }
    __syncthreads();
#pragma unroll
    for (int ks = 0; ks < 2; ++ks) {
      const int kblk = k0 * 2 + ks;
      short8 a[2], b[4];
#pragma unroll
      for (int mt = 0; mt < 2; ++mt) {
        const int row = mt * 16 + lm;
        a[mt] = *(const short8*)(Xs + row * 80 + (((ks * 4 + qq)) ^ (row & 7)) * 8);
      }
#pragma unroll
      for (int nt = 0; nt < 4; ++nt)
        b[nt] = *(const short8*)(Wf + ((size_t)(kblk * 16 + w * 4 + nt) * 64 + ln) * 8);
#pragma unroll
      for (int mt = 0; mt < 2; ++mt)
#pragma unroll
        for (int nt = 0; nt < 4; ++nt)
          acc[mt][nt] = __builtin_amdgcn_mfma_f32_16x16x32_bf16(a[mt], b[nt], acc[mt][nt], 0, 0, 0);
    }
  }
#pragma unroll
  for (int mt = 0; mt < 2; ++mt)
#pragma unroll
    for (int nt = 0; nt < 4; ++nt) {
      const int n = w * 64 + nt * 16 + lm;
      const float bval = bo[n];
      const int m0 = bm * 32 + mt * 16 + qq * 4;
#pragma unroll
      for (int r = 0; r < 4; ++r)
        __builtin_nontemporal_store(acc[mt][nt][r] + bval, out + (size_t)(m0 + r) * 256 + n);
    }
}

// ======================= fused attention ===================================
template <int NP>
DEV void phase2(short* ss, float* shead, int row0, int w, int ln, float g) {
  const int c0 = ln * 4;
  for (int rr = 0; rr < 4; ++rr) {
    const int m = w * 4 + rr;
    const int irow = row0 + m;
    short* srow = ss + m * SST;

    float sv[NP * 4], e[NP * 4];
    float lm1 = -INFINITY;
#pragma unroll
    for (int p = 0; p < NP; ++p) {
      const uint2 u = *(const uint2*)(srow + p * 256 + c0);
      const float2 f0 = __half22float2(*(const __half2*)&u.x);
      const float2 f1 = __half22float2(*(const __half2*)&u.y);
      sv[p * 4 + 0] = f0.x; sv[p * 4 + 1] = f0.y;
      sv[p * 4 + 2] = f1.x; sv[p * 4 + 3] = f1.y;
#pragma unroll
      for (int j = 0; j < 4; ++j)
        if (p * 256 + c0 + j <= irow) lm1 = fmaxf(lm1, sv[p * 4 + j]);
    }
    const float m1 = wmax(lm1);

    float carry = 0.f, excl[NP];
#pragma unroll
    for (int p = 0; p < NP; ++p) {
      float ls = 0.f;
#pragma unroll
      for (int j = 0; j < 4; ++j) {
        const int c = p * 256 + c0 + j;
        e[p * 4 + j] = (c <= irow) ? __expf(sv[p * 4 + j] - m1) : 0.f;
        ls += e[p * 4 + j];
      }
      const float incl = wscan_incl(ls);
      excl[p] = carry + incl - ls;
      carry += __shfl(incl, 63, 64);
    }
    const float Z = carry, invZ = 1.f / Z;

    float lm2 = -INFINITY;
#pragma unroll
    for (int p = 0; p < NP; ++p) {
      float cum = excl[p];
#pragma unroll
      for (int j = 0; j < 4; ++j) {
        const int c = p * 256 + c0 + j;
        cum += e[p * 4 + j];
        const float tail = (Z - cum) * invZ;
        const float pos = (float)(irow - c);
        const float dist = sqrtf(fmaxf(tail * pos, 0.f));
        float eff = __expf(g * dist);
        eff = fminf(fmaxf(eff, 1e-5f), 1e5f);
        const float s2 = sv[p * 4 + j] * eff;
        sv[p * 4 + j] = s2;
        if (c <= irow) lm2 = fmaxf(lm2, s2);
      }
    }
    const float m2 = wmax(lm2);

    float ls2 = 0.f;
#pragma unroll
    for (int p = 0; p < NP; ++p)
#pragma unroll
      for (int j = 0; j < 4; ++j) {
        const int c = p * 256 + c0 + j;
        e[p * 4 + j] = (c <= irow) ? __expf(sv[p * 4 + j] - m2) : 0.f;
        ls2 += e[p * 4 + j];
      }
    const float i2 = 1.f / wsum(ls2);

    float* grow = shead + (size_t)irow * Ssz;
#pragma unroll
    for (int p = 0; p < NP; ++p) {
      floatx4 o;
      o.x = e[p * 4 + 0] * i2; o.y = e[p * 4 + 1] * i2;
      o.z = e[p * 4 + 2] * i2; o.w = e[p * 4 + 3] * i2;
      __builtin_nontemporal_store(o, (floatx4*)(grow + p * 256 + c0));
      uint2 pk;
      pk.x = (uint)(unsigned short)f2bf(o.x) | ((uint)(unsigned short)f2bf(o.y) << 16);
      pk.y = (uint)(unsigned short)f2bf(o.z) | ((uint)(unsigned short)f2bf(o.w) << 16);
      *(uint2*)(srow + p * 256 + c0) = pk;
    }
  }
}

__global__ __launch_bounds__(256, 4) void attn_kernel(
    const short* __restrict__ qh, const short* __restrict__ kh,
    const short* __restrict__ vt, const float* __restrict__ gammas,
    float* __restrict__ scores_out, short* __restrict__ oc) {
  __shared__ short ss[16 * SST];

  const int tid = threadIdx.x, ln = tid & 63, w = tid >> 6;
  const int lm = ln & 15, qq = ln >> 4;
  const int bh = blockIdx.x >> 6;
  const int row0 = (63 - (blockIdx.x & 63)) << 4;  // heavy tiles first
  const int h = bh & 7, b = bh >> 3;
  const float scale = 0.17677669529663687f;
  const float g = -fabsf(gammas[h]);

  const short* qhead = qh + (size_t)bh * Ssz * DHn;
  const short* khead = kh + (size_t)bh * Ssz * DHn;
  const short* vhead = vt + (size_t)bh * DHn * Ssz;
  float* shead = scores_out + ((size_t)bh << 20);

  const short8 qa = *(const short8*)(qhead + (row0 + lm) * DHn + qq * 8);

  // phase 1: QK^T -> fp16 raw scores in LDS (causal tiles only)
  const int ntile = (row0 >> 4) + 1;
  for (int t = w; t < ntile; t += 4) {
    const int n0 = t * 16;
    const short8 kb = *(const short8*)(khead + (n0 + lm) * DHn + qq * 8);
    floatx4 c = {0.f, 0.f, 0.f, 0.f};
    c = __builtin_amdgcn_mfma_f32_16x16x32_bf16(qa, kb, c, 0, 0, 0);
#pragma unroll
    for (int r = 0; r < 4; ++r)
      ss[(qq * 4 + r) * SST + n0 + lm] = f2h(c[r] * scale);
  }
  __syncthreads();

  // phase 2
  const int NPc = (row0 >> 8) + 1;
  switch (NPc) {
    case 1: phase2<1>(ss, shead, row0, w, ln, g); break;
    case 2: phase2<2>(ss, shead, row0, w, ln, g); break;
    case 3: phase2<3>(ss, shead, row0, w, ln, g); break;
    default: phase2<4>(ss, shead, row0, w, ln, g); break;
  }

  // zero-fill masked tail of scores rows (non-temporal)
  if (NPc < 4) {
    const floatx4 z4 = {0.f, 0.f, 0.f, 0.f};
    for (int r = 0; r < 16; ++r) {
      float* grow = shead + (size_t)(row0 + r) * Ssz + NPc * 256;
      for (int i = tid; i < (4 - NPc) * 64; i += 256)
        __builtin_nontemporal_store(z4, ((floatx4*)grow) + i);
    }
  }
  __syncthreads();

  // phase 3: PV via MFMA
  floatx4 o0 = {0.f, 0.f, 0.f, 0.f}, o1 = {0.f, 0.f, 0.f, 0.f};
  const int nkt = (row0 >> 5) + 1;
  for (int kt = w; kt < nkt; kt += 4) {
    const int k0 = kt * 32;
    const short8 av = *(const short8*)(ss + lm * SST + k0 + qq * 8);
    const short8 b0 = *(const short8*)(vhead + (lm << 10) + k0 + qq * 8);
    const short8 b1 = *(const short8*)(vhead + ((16 + lm) << 10) + k0 + qq * 8);
    o0 = __builtin_amdgcn_mfma_f32_16x16x32_bf16(av, b0, o0, 0, 0, 0);
    o1 = __builtin_amdgcn_mfma_f32_16x16x32_bf16(av, b1, o1, 0, 0, 0);
  }
  __syncthreads();
  float* red = (float*)ss;  // alias, 8 KB
#pragma unroll
  for (int r = 0; r < 4; ++r) {
    red[(w * 16 + qq * 4 + r) * 32 + lm] = o0[r];
    red[(w * 16 + qq * 4 + r) * 32 + 16 + lm] = o1[r];
  }
  __syncthreads();
  {
    const int m = tid >> 4, n = tid & 15;
    float a0 = 0.f, a1 = 0.f;
#pragma unroll
    for (int wv = 0; wv < 4; ++wv) {
      a0 += red[(wv * 16 + m) * 32 + n];
      a1 += red[(wv * 16 + m) * 32 + 16 + n];
    }
    const size_t row = ((size_t)b << 10) + row0 + m;
    oc[row * Dsz + h * DHn + n] = f2bf(a0);
    oc[row * Dsz + h * DHn + 16 + n] = f2bf(a1);
  }
}

// ---------------- launch ---------------------------------------------------
extern "C" void kernel_launch(void* const* d_in, const int* in_sizes, int n_in,
                              void* d_out, int out_size, void* d_ws, size_t ws_size,
                              hipStream_t stream) {
  const float* q  = (const float*)d_in[0];
  const float* k  = (const float*)d_in[1];
  const float* v  = (const float*)d_in[2];
  const float* Wq = (const float*)d_in[4];
  const float* bq = (const float*)d_in[5];
  const float* Wv = (const float*)d_in[6];
  const float* bv = (const float*)d_in[7];
  const float* Wo = (const float*)d_in[8];
  const float* bo = (const float*)d_in[9];
  const float* gm = (const float*)d_in[10];

  float* out    = (float*)d_out;                  // [B,S,D] fp32
  float* scores = out + (size_t)Bsz * Ssz * Dsz;  // [B,H,S,S] fp32

  const size_t Q = (size_t)Bsz * Hn * Ssz * DHn;
  short* qh = (short*)d_ws;        // bf16 [B,H,S,DH]
  short* kh = qh + Q;
  short* vt = kh + Q;              // bf16 [B,H,DH,S]
  short* oc = vt + Q;              // bf16 [B,S,D]
  short* Wf = oc + Q;              // bf16 frag-order weights, 3 x 65536

  const dim3 blk(256);
  hipLaunchKernelGGL(cvt_wfrag, dim3(32, 3), blk, 0, stream, Wq, Wv, Wo, Wf);
  hipLaunchKernelGGL(proj_qkv2, dim3(256, 3), blk, 0, stream,
                     q, k, v, Wf, bq, bv, qh, kh, vt);
  hipLaunchKernelGGL(attn_kernel, dim3(Bsz * Hn * (Ssz / 16)), blk, 0, stream,
                     qh, kh, vt, gm, scores, oc);
  hipLaunchKernelGGL(proj_out2, dim3(256), blk, 0, stream, oc, Wf, bo, out);
}